// Round 7
// baseline (108.130 us; speedup 1.0000x reference)
//
#include <hip/hip_runtime.h>
#include <math.h>

#define T_   2048
#define NB_  64
#define NU_  8
#define NY_  8
#define NH_  256
#define H2_  128
#define CCH  64      // number of chunks
#define LCH  32      // chunk length = T_/CCH

static const float PI_HALF = 1.5707963267948966f;

typedef _Float16 half8  __attribute__((ext_vector_type(8)));
typedef __fp16   fp16x2 __attribute__((ext_vector_type(2)));   // cvt_pkrtz return type
typedef float    f32x4  __attribute__((ext_vector_type(4)));

// ws layout:
//   M     (f16 [R=256][m=256])  : 128 KB  @ 0
//   c_buf (f32 [k][b][pair][2]) : 4 MB    @ 128K
//   initT (f16 [k][b=64][m=256]): 1 MB    @ 128K+4M
// K-index m = 2*h + comp  (comp0 = x1-part, comp1 = x2-part)

// ---------------- kernel 1: scan from zero + MFMA projection + endpoint ------
// Lane j owns pairs 2j, 2j+1 -> channels 2j, 2j+1, 2j+128, 2j+129.
__global__ __launch_bounds__(64) void k_scanproj(
    const float* __restrict__ U, const float* __restrict__ lr,
    const float* __restrict__ li, const float* __restrict__ B,
    const float* __restrict__ mult, const float* __restrict__ Wx2y,
    const float* __restrict__ bx2y, float* __restrict__ c_buf,
    float* __restrict__ Y)
{
    const int k = blockIdx.x >> 6;
    const int b = blockIdx.x & 63;
    const int j = threadIdx.x;
    const int c0 = 2*j;

    float2 lrv = *(const float2*)(lr + c0);
    float2 liv = *(const float2*)(li + c0);
    float rA  = expf(-fabsf(lrv.x)), thA = PI_HALF*liv.x;
    float reA = rA*cosf(thA), imA = rA*sinf(thA);
    float rB  = expf(-fabsf(lrv.y)), thB = PI_HALF*liv.y;
    float reB = rB*cosf(thB), imB = rB*sinf(thB);

    float Ba1[NU_], Ba2[NU_], Bb1[NU_], Bb2[NU_];
    {
        float s1 = expf(mult[c0]),     s2 = expf(mult[c0+128]);
        float s3 = expf(mult[c0+1]),   s4 = expf(mult[c0+129]);
        #pragma unroll
        for (int i = 0; i < NU_; i++) {
            Ba1[i] = B[(c0    )*NU_ + i] * s1;
            Bb1[i] = B[(c0+  1)*NU_ + i] * s3;
            Ba2[i] = B[(c0+128)*NU_ + i] * s2;
            Bb2[i] = B[(c0+129)*NU_ + i] * s4;
        }
    }

    // MFMA B-operand: Wx2y as f16, lane l holds k = q*32 + (l>>4)*8 + i, n = l&15
    const int yv  = j & 15;
    const int kg  = j >> 4;
    half8 wf[8];
    #pragma unroll
    for (int q = 0; q < 8; q++) {
        half8 f;
        if (yv < 8) {
            const float* wr = Wx2y + yv*NH_ + q*32 + kg*8;
            #pragma unroll
            for (int i = 0; i < 8; i++) f[i] = (_Float16)wr[i];
        } else {
            #pragma unroll
            for (int i = 0; i < 8; i++) f[i] = (_Float16)0.f;
        }
        wf[q] = f;
    }
    const float bias = bx2y[yv & 7];

    __shared__ _Float16 xS[16*256];       // 8 KB
    uint32_t* xS32 = (uint32_t*)xS;

    float xa1=0.f, xa2=0.f, xb1=0.f, xb2=0.f;
    const float4* Ut = (const float4*)(U + ((size_t)(k*LCH)*NB_ + b)*NU_);

    float4 u0 = Ut[0], u1 = Ut[1];        // 1-ahead prefetch pipeline

    for (int s = 0; s < LCH/16; s++) {
        #pragma unroll 4
        for (int t16 = 0; t16 < 16; t16++) {
            const int t = s*16 + t16;
            float4 cu0 = u0, cu1 = u1;
            const int tn = (t < LCH-1) ? t+1 : t;
            u0 = Ut[tn*128 + 0];
            u1 = Ut[tn*128 + 1];

            float u[NU_] = {cu0.x,cu0.y,cu0.z,cu0.w,cu1.x,cu1.y,cu1.z,cu1.w};
            float ba1=0.f, ba2=0.f, bb1=0.f, bb2=0.f;
            #pragma unroll
            for (int i = 0; i < NU_; i++) {
                ba1 = fmaf(u[i], Ba1[i], ba1);
                ba2 = fmaf(u[i], Ba2[i], ba2);
                bb1 = fmaf(u[i], Bb1[i], bb1);
                bb2 = fmaf(u[i], Bb2[i], bb2);
            }
            float na1 = fmaf(reA, xa1, fmaf(-imA, xa2, ba1));
            float na2 = fmaf(imA, xa1, fmaf( reA, xa2, ba2));
            float nb1 = fmaf(reB, xb1, fmaf(-imB, xb2, bb1));
            float nb2 = fmaf(imB, xb1, fmaf( reB, xb2, bb2));
            xa1=na1; xa2=na2; xb1=nb1; xb2=nb2;

            union { fp16x2 h; uint32_t u32; } p0, p1;
            p0.h = __builtin_amdgcn_cvt_pkrtz(xa1, xb1);   // chans 2j, 2j+1
            p1.h = __builtin_amdgcn_cvt_pkrtz(xa2, xb2);   // chans 2j+128, 2j+129
            const int w0 = t16*128 + (((j>>2) ^ t16) << 2) + (j & 3);
            xS32[w0]      = p0.u32;
            xS32[w0 + 64] = p1.u32;
        }
        __syncthreads();

        f32x4 acc = {0.f, 0.f, 0.f, 0.f};
        #pragma unroll
        for (int q = 0; q < 8; q++) {
            const int p = ((q << 2) + kg) ^ yv;
            const half8* ap = (const half8*)(xS + (yv << 8) + (p << 3));
            acc = __builtin_amdgcn_mfma_f32_16x16x32_f16(*ap, wf[q], acc, 0, 0, 0);
        }
        __syncthreads();

        if (yv < 8) {
            #pragma unroll
            for (int r = 0; r < 4; r++) {
                const int tg = k*LCH + s*16 + kg*4 + r;   // C row = t
                Y[((size_t)tg*NB_ + b)*NY_ + yv] = acc[r] + bias;
            }
        }
    }

    // endpoint of zero-init scan -> c_buf[k][b][pair][2]
    *(float4*)(c_buf + ((size_t)(k*NB_ + b))*(H2_*2) + 4*j) =
        make_float4(xa1, xa2, xb1, xb2);
}

// ---------------- kernel 2: chunk prefix -> f16 transposed inits --------------
__global__ __launch_bounds__(64) void k_prefix(
    const float* __restrict__ y0, const float* __restrict__ lr,
    const float* __restrict__ li, const float* __restrict__ Wy2x,
    const float* __restrict__ by2x, const float* __restrict__ c_buf,
    uint32_t* __restrict__ initT)
{
    const int g = blockIdx.x*64 + threadIdx.x;   // 0..8191
    const int b = g >> 7;
    const int h = g & 127;                       // pair index

    float x1 = by2x[h], x2 = by2x[h+H2_];
    #pragma unroll
    for (int y = 0; y < NY_; y++) {
        float yy = y0[b*NY_ + y];
        x1 = fmaf(yy, Wy2x[h*NY_ + y],        x1);
        x2 = fmaf(yy, Wy2x[(h+H2_)*NY_ + y],  x2);
    }

    float rL  = expf(-(float)LCH * fabsf(lr[h]));
    float thL = (float)LCH * PI_HALF * li[h];
    float reL = rL * cosf(thL), imL = rL * sinf(thL);

    #pragma unroll 8
    for (int k = 0; k < CCH; k++) {
        float2 c = *(const float2*)(c_buf + (size_t)k*16384 + b*256 + 2*h);
        union { fp16x2 hh; uint32_t u32; } pk;
        pk.hh = __builtin_amdgcn_cvt_pkrtz(x1, x2);     // m=2h (lo), m=2h+1 (hi)
        initT[(size_t)k*8192 + b*128 + h] = pk.u32;
        float n1 = fmaf(reL, x1, fmaf(-imL, x2, c.x));
        float n2 = fmaf(imL, x1, fmaf( reL, x2, c.y));
        x1 = n1; x2 = n2;
    }
}

// ---------------- kernel 3: M[δ,y][m] = fold of W·Λ^(δ+1), f16 ---------------
__global__ __launch_bounds__(64) void k_mcoef(
    const float* __restrict__ lr, const float* __restrict__ li,
    const float* __restrict__ Wx2y, uint32_t* __restrict__ M32)
{
    const int R = blockIdx.x;          // 0..255 = δ*8 + y
    const int dlt = R >> 3, y = R & 7;
    const float e = (float)(dlt + 1);
    const int j = threadIdx.x;

    #pragma unroll
    for (int hh = 0; hh < 2; hh++) {
        const int h = j + hh*64;
        float r  = expf(-e * fabsf(lr[h]));
        float an = e * PI_HALF * li[h];
        float c = r * cosf(an), s = r * sinf(an);
        float W1 = Wx2y[y*NH_ + h];
        float W2 = Wx2y[y*NH_ + h + H2_];
        float Mre = fmaf(W1, c,  W2 * s);     // multiplies i1  (m=2h)
        float Mim = fmaf(W2, c, -W1 * s);     // multiplies i2  (m=2h+1)
        union { fp16x2 hh2; uint32_t u32; } pk;
        pk.hh2 = __builtin_amdgcn_cvt_pkrtz(Mre, Mim);
        M32[R*128 + hh*64 + j] = pk.u32;
    }
}

// ---------------- kernel 4: correction GEMM, Y += M @ init_k -----------------
// 128 blocks = (chunk k, col-half) ; 256 threads = 4 waves.
// C tile per block: 256 rows (R) x 32 cols (b). Wave w: rows [w*64, w*64+64).
__global__ __launch_bounds__(256) void k_corr(
    const _Float16* __restrict__ M, const uint32_t* __restrict__ initT,
    float* __restrict__ Y)
{
    const int k    = blockIdx.x >> 1;
    const int half = blockIdx.x & 1;
    const int tid  = threadIdx.x;
    const int w    = tid >> 6, l = tid & 63;
    const int lane16 = l & 15, kg = l >> 4;

    __shared__ _Float16 bS[32*264];     // 32 b-rows, padded stride 264 f16
    {
        uint32_t* bS32 = (uint32_t*)bS;
        const int r = tid >> 3, seg = tid & 7;        // 32 rows x 8 threads
        const uint32_t* src = initT + (size_t)k*8192 + (half*32 + r)*128 + seg*16;
        uint32_t* dst = bS32 + r*132 + seg*16;
        ((uint4*)dst)[0] = ((const uint4*)src)[0];
        ((uint4*)dst)[1] = ((const uint4*)src)[1];
        ((uint4*)dst)[2] = ((const uint4*)src)[2];
        ((uint4*)dst)[3] = ((const uint4*)src)[3];
    }
    __syncthreads();

    #pragma unroll
    for (int rt = 0; rt < 4; rt++) {
        const int R0 = w*64 + rt*16;
        half8 af[8];
        #pragma unroll
        for (int q = 0; q < 8; q++)
            af[q] = *(const half8*)(M + (size_t)(R0 + lane16)*256 + q*32 + kg*8);

        f32x4 acc0 = {0.f,0.f,0.f,0.f}, acc1 = {0.f,0.f,0.f,0.f};
        #pragma unroll
        for (int q = 0; q < 8; q++) {
            const half8* b0 = (const half8*)(bS + ( 0 + lane16)*264 + q*32 + kg*8);
            const half8* b1 = (const half8*)(bS + (16 + lane16)*264 + q*32 + kg*8);
            acc0 = __builtin_amdgcn_mfma_f32_16x16x32_f16(af[q], *b0, acc0, 0, 0, 0);
            acc1 = __builtin_amdgcn_mfma_f32_16x16x32_f16(af[q], *b1, acc1, 0, 0, 0);
        }

        #pragma unroll
        for (int r4 = 0; r4 < 4; r4++) {
            const int R = R0 + kg*4 + r4;
            const int t = k*LCH + (R >> 3);
            const int y = R & 7;
            float* yp0 = Y + ((size_t)t*NB_ + half*32 +  0 + lane16)*NY_ + y;
            float* yp1 = Y + ((size_t)t*NB_ + half*32 + 16 + lane16)*NY_ + y;
            *yp0 += acc0[r4];
            *yp1 += acc1[r4];
        }
    }
}

extern "C" void kernel_launch(void* const* d_in, const int* in_sizes, int n_in,
                              void* d_out, int out_size, void* d_ws, size_t ws_size,
                              hipStream_t stream) {
    const float* y0   = (const float*)d_in[0];
    const float* U    = (const float*)d_in[1];
    const float* lr   = (const float*)d_in[2];
    const float* li   = (const float*)d_in[3];
    const float* B    = (const float*)d_in[4];
    const float* mult = (const float*)d_in[5];
    const float* Wy2x = (const float*)d_in[6];
    const float* by2x = (const float*)d_in[7];
    const float* Wx2y = (const float*)d_in[8];
    const float* bx2y = (const float*)d_in[9];
    float* Y = (float*)d_out;

    uint32_t*  Mbuf  = (uint32_t*)d_ws;                                  // 128 KB
    float*     c_buf = (float*)((char*)d_ws + (128<<10));                // 4 MB
    uint32_t*  initT = (uint32_t*)((char*)d_ws + (128<<10) + (4<<20));   // 1 MB

    k_mcoef   <<<256, 64, 0, stream>>>(lr, li, Wx2y, Mbuf);
    k_scanproj<<<CCH*NB_, 64, 0, stream>>>(U, lr, li, B, mult, Wx2y, bx2y, c_buf, Y);
    k_prefix  <<<(NB_*H2_)/64, 64, 0, stream>>>(y0, lr, li, Wy2x, by2x, c_buf, initT);
    k_corr    <<<CCH*2, 256, 0, stream>>>((const _Float16*)Mbuf, initT, Y);
}

// Round 8
// 104.494 us; speedup vs baseline: 1.0348x; 1.0348x over previous
//
#include <hip/hip_runtime.h>
#include <math.h>

#define T_   2048
#define NB_  64
#define NU_  8
#define NY_  8
#define NH_  256
#define H2_  128
#define CCH  64      // number of chunks
#define LCH  32      // chunk length = T_/CCH

static const float PI_HALF = 1.5707963267948966f;

typedef _Float16 half8  __attribute__((ext_vector_type(8)));
typedef __fp16   fp16x2 __attribute__((ext_vector_type(2)));   // cvt_pkrtz return type
typedef float    f32x4  __attribute__((ext_vector_type(4)));

// m-ordering (K dim of all MFMAs): m = 2h + comp. comp0 = x1 (chan h),
// comp1 = x2 (chan h+128). One dword holds the (x1,x2) f16 pair of pair h.
//
// ws layout: M (f16[256R][256m]) 128 KB | c_buf (f32[k][b][pair][2]) 4 MB |
//            initT (f16[k][b][256m]) 2 MB

// ---------------- kernel 1: scan from zero + K-split MFMA projection ---------
// 128 threads = 2 waves. Thread tid owns pair h = tid (chans h, h+128).
__global__ __launch_bounds__(128) void k_scanproj(
    const float* __restrict__ U, const float* __restrict__ lr,
    const float* __restrict__ li, const float* __restrict__ B,
    const float* __restrict__ mult, const float* __restrict__ Wx2y,
    const float* __restrict__ bx2y, float* __restrict__ c_buf,
    float* __restrict__ Y)
{
    const int k   = blockIdx.x >> 6;
    const int b   = blockIdx.x & 63;
    const int tid = threadIdx.x;
    const int h   = tid;            // pair index 0..127
    const int w   = tid >> 6;       // wave
    const int l   = tid & 63;       // lane in wave
    const int row = l & 15;         // MFMA A-row / C-col
    const int kg  = (l >> 4) & 3;

    // lambda for pair h
    float rr = expf(-fabsf(lr[h]));
    float th = PI_HALF * li[h];
    float re = rr * cosf(th), im = rr * sinf(th);

    // B rows (scaled) for chans h, h+128
    float B1[NU_], B2[NU_];
    {
        float s1 = expf(mult[h]), s2 = expf(mult[h+H2_]);
        float4 b1a = *(const float4*)(B + h*NU_);
        float4 b1b = *(const float4*)(B + h*NU_ + 4);
        float4 b2a = *(const float4*)(B + (h+H2_)*NU_);
        float4 b2b = *(const float4*)(B + (h+H2_)*NU_ + 4);
        B1[0]=b1a.x*s1; B1[1]=b1a.y*s1; B1[2]=b1a.z*s1; B1[3]=b1a.w*s1;
        B1[4]=b1b.x*s1; B1[5]=b1b.y*s1; B1[6]=b1b.z*s1; B1[7]=b1b.w*s1;
        B2[0]=b2a.x*s2; B2[1]=b2a.y*s2; B2[2]=b2a.z*s2; B2[3]=b2a.w*s2;
        B2[4]=b2b.x*s2; B2[5]=b2b.y*s2; B2[6]=b2b.z*s2; B2[7]=b2b.w*s2;
    }

    // W fragments for this wave's K-half (q = 4w+q'), m-interleaved:
    // f16 pair at dword = (Wx2y[y][hh], Wx2y[y][hh+128])
    half8 wf[4];
    #pragma unroll
    for (int q2 = 0; q2 < 4; q2++) {
        const int q = 4*w + q2;
        union { uint32_t u32[4]; half8 h8; } fu;
        if (row < 8) {
            const int hh = q*16 + kg*4;     // base pair for this 8-f16 chunk
            const float* lo = Wx2y + row*NH_ + hh;
            const float* hi = lo + H2_;
            #pragma unroll
            for (int i = 0; i < 4; i++) {
                union { fp16x2 h2; uint32_t u; } pk;
                pk.h2 = __builtin_amdgcn_cvt_pkrtz(lo[i], hi[i]);
                fu.u32[i] = pk.u;
            }
        } else {
            fu.u32[0]=0; fu.u32[1]=0; fu.u32[2]=0; fu.u32[3]=0;
        }
        wf[q2] = fu.h8;
    }
    const float bias = bx2y[tid & 7];

    __shared__ float    uS[LCH*NU_];    // 1 KB: whole chunk of U for this b
    __shared__ _Float16 xS[16*256];     // 8 KB: one 16-t state tile (m-order)
    __shared__ float    pS[4*132];      // ~2.1 KB: K-split C partials
    uint32_t* xS32 = (uint32_t*)xS;

    if (tid < 64) {                     // bulk coalesced U stage: 1 KB
        ((float4*)uS)[tid] =
            *(const float4*)(U + ((size_t)(k*LCH + (tid>>1))*NB_ + b)*NU_ + (tid&1)*4);
    }
    __syncthreads();

    float x1 = 0.f, x2 = 0.f;
    const int g = h >> 2;               // 16-B group of this pair's dword

    for (int s = 0; s < 2; s++) {
        #pragma unroll 4
        for (int t16 = 0; t16 < 16; t16++) {
            const int t = s*16 + t16;
            float4 u0 = ((const float4*)uS)[2*t+0];   // wave-uniform broadcast
            float4 u1 = ((const float4*)uS)[2*t+1];
            float u[NU_] = {u0.x,u0.y,u0.z,u0.w,u1.x,u1.y,u1.z,u1.w};
            float bu1=0.f, bu2=0.f;
            #pragma unroll
            for (int i = 0; i < NU_; i++) {
                bu1 = fmaf(u[i], B1[i], bu1);
                bu2 = fmaf(u[i], B2[i], bu2);
            }
            float n1 = fmaf(re, x1, fmaf(-im, x2, bu1));
            float n2 = fmaf(im, x1, fmaf( re, x2, bu2));
            x1 = n1; x2 = n2;

            union { fp16x2 h2; uint32_t u32; } pk;
            pk.h2 = __builtin_amdgcn_cvt_pkrtz(x1, x2);
            xS32[t16*128 + ((g ^ t16) & 31)*4 + (h & 3)] = pk.u32;
        }
        __syncthreads();

        // K-split MFMA: wave w covers K = 128w .. 128w+127
        f32x4 acc = {0.f,0.f,0.f,0.f};
        #pragma unroll
        for (int q2 = 0; q2 < 4; q2++) {
            const int q = 4*w + q2;
            const int p = ((q << 2) + kg) ^ row;
            const half8* ap = (const half8*)(xS + (row << 8) + (p << 3));
            acc = __builtin_amdgcn_mfma_f32_16x16x32_f16(*ap, wf[q2], acc, 0, 0, 0);
        }
        #pragma unroll
        for (int r = 0; r < 4; r++) pS[r*132 + w*64 + l] = acc[r];
        __syncthreads();

        // 128 threads: cross-wave K-reduce + Y store
        {
            const int t  = tid >> 3, y = tid & 7;
            const int ls = ((t >> 2) << 4) + y;     // source lane for C(t,y)
            const int rg = t & 3;
            float sum = pS[rg*132 + ls] + pS[rg*132 + 64 + ls];
            Y[((size_t)(k*LCH + s*16 + t)*NB_ + b)*NY_ + y] = sum + bias;
        }
    }

    // endpoint of zero-init scan
    *(float2*)(c_buf + (size_t)(k*NB_ + b)*(H2_*2) + 2*h) = make_float2(x1, x2);
}

// ---------------- kernel 2: prefix combine (+f16 inits) AND M coefficients ---
__global__ __launch_bounds__(64) void k_mid(
    const float* __restrict__ y0, const float* __restrict__ lr,
    const float* __restrict__ li, const float* __restrict__ Wy2x,
    const float* __restrict__ by2x, const float* __restrict__ Wx2y,
    const float* __restrict__ c_buf, uint32_t* __restrict__ initT,
    uint32_t* __restrict__ M32)
{
    const int bi = blockIdx.x;
    const int j  = threadIdx.x;

    if (bi < 128) {
        // ---- prefix: per (b, pair h) chain over chunks ----
        const int gidx = bi*64 + j;
        const int b = gidx >> 7;
        const int h = gidx & 127;

        float x1 = by2x[h], x2 = by2x[h+H2_];
        #pragma unroll
        for (int y = 0; y < NY_; y++) {
            float yy = y0[b*NY_ + y];
            x1 = fmaf(yy, Wy2x[h*NY_ + y],        x1);
            x2 = fmaf(yy, Wy2x[(h+H2_)*NY_ + y],  x2);
        }

        float rL  = expf(-(float)LCH * fabsf(lr[h]));
        float thL = (float)LCH * PI_HALF * li[h];
        float reL = rL * cosf(thL), imL = rL * sinf(thL);

        #pragma unroll 8
        for (int k = 0; k < CCH; k++) {
            float2 c = *(const float2*)(c_buf + (size_t)k*16384 + b*256 + 2*h);
            union { fp16x2 hh; uint32_t u32; } pk;
            pk.hh = __builtin_amdgcn_cvt_pkrtz(x1, x2);   // m=2h, m=2h+1
            initT[(size_t)k*8192 + b*128 + h] = pk.u32;
            float n1 = fmaf(reL, x1, fmaf(-imL, x2, c.x));
            float n2 = fmaf(imL, x1, fmaf( reL, x2, c.y));
            x1 = n1; x2 = n2;
        }
    } else {
        // ---- M[R=δ*8+y][m] = W·Λ^(δ+1) fold, f16 ----
        const int R = bi - 128;
        const int dlt = R >> 3, y = R & 7;
        const float e = (float)(dlt + 1);
        #pragma unroll
        for (int hh = 0; hh < 2; hh++) {
            const int h = j + hh*64;
            float r  = expf(-e * fabsf(lr[h]));
            float an = e * PI_HALF * li[h];
            float c = r * cosf(an), sn = r * sinf(an);
            float W1 = Wx2y[y*NH_ + h];
            float W2 = Wx2y[y*NH_ + h + H2_];
            float Mre = fmaf(W1, c,  W2 * sn);
            float Mim = fmaf(W2, c, -W1 * sn);
            union { fp16x2 h2; uint32_t u32; } pk;
            pk.h2 = __builtin_amdgcn_cvt_pkrtz(Mre, Mim);
            M32[R*128 + hh*64 + j] = pk.u32;
        }
    }
}

// ---------------- kernel 3: correction GEMM, Y += M @ init_k -----------------
// 128 blocks = (chunk k, b-half); 256 threads = 4 waves; C: 256R x 32b.
__global__ __launch_bounds__(256) void k_corr(
    const _Float16* __restrict__ M, const uint32_t* __restrict__ initT,
    float* __restrict__ Y)
{
    const int k    = blockIdx.x >> 1;
    const int half = blockIdx.x & 1;
    const int tid  = threadIdx.x;
    const int w    = tid >> 6, l = tid & 63;
    const int lane16 = l & 15, kg = l >> 4;

    __shared__ _Float16 bS[32*264];     // 32 b-rows, padded stride 264 f16
    {
        uint32_t* bS32 = (uint32_t*)bS;
        const int r = tid >> 3, seg = tid & 7;
        const uint32_t* src = initT + (size_t)k*8192 + (half*32 + r)*128 + seg*16;
        uint32_t* dst = bS32 + r*132 + seg*16;
        ((uint4*)dst)[0] = ((const uint4*)src)[0];
        ((uint4*)dst)[1] = ((const uint4*)src)[1];
        ((uint4*)dst)[2] = ((const uint4*)src)[2];
        ((uint4*)dst)[3] = ((const uint4*)src)[3];
    }
    __syncthreads();

    #pragma unroll
    for (int rt = 0; rt < 4; rt++) {
        const int R0 = w*64 + rt*16;
        half8 af[8];
        #pragma unroll
        for (int q = 0; q < 8; q++)
            af[q] = *(const half8*)(M + (size_t)(R0 + lane16)*256 + q*32 + kg*8);

        f32x4 acc0 = {0.f,0.f,0.f,0.f}, acc1 = {0.f,0.f,0.f,0.f};
        #pragma unroll
        for (int q = 0; q < 8; q++) {
            const half8* b0 = (const half8*)(bS + ( 0 + lane16)*264 + q*32 + kg*8);
            const half8* b1 = (const half8*)(bS + (16 + lane16)*264 + q*32 + kg*8);
            acc0 = __builtin_amdgcn_mfma_f32_16x16x32_f16(af[q], *b0, acc0, 0, 0, 0);
            acc1 = __builtin_amdgcn_mfma_f32_16x16x32_f16(af[q], *b1, acc1, 0, 0, 0);
        }

        // regs r4=0..3 are 4 consecutive y's -> float4 RMW
        const int t  = k*LCH + (R0 >> 3) + (kg >> 1);
        const int y0 = (kg & 1) * 4;
        float4* yp0 = (float4*)(Y + ((size_t)t*NB_ + half*32 +  0 + lane16)*NY_ + y0);
        float4* yp1 = (float4*)(Y + ((size_t)t*NB_ + half*32 + 16 + lane16)*NY_ + y0);
        float4 o0 = *yp0, o1 = *yp1;
        o0.x += acc0[0]; o0.y += acc0[1]; o0.z += acc0[2]; o0.w += acc0[3];
        o1.x += acc1[0]; o1.y += acc1[1]; o1.z += acc1[2]; o1.w += acc1[3];
        *yp0 = o0; *yp1 = o1;
    }
}

extern "C" void kernel_launch(void* const* d_in, const int* in_sizes, int n_in,
                              void* d_out, int out_size, void* d_ws, size_t ws_size,
                              hipStream_t stream) {
    const float* y0   = (const float*)d_in[0];
    const float* U    = (const float*)d_in[1];
    const float* lr   = (const float*)d_in[2];
    const float* li   = (const float*)d_in[3];
    const float* B    = (const float*)d_in[4];
    const float* mult = (const float*)d_in[5];
    const float* Wy2x = (const float*)d_in[6];
    const float* by2x = (const float*)d_in[7];
    const float* Wx2y = (const float*)d_in[8];
    const float* bx2y = (const float*)d_in[9];
    float* Y = (float*)d_out;

    uint32_t* Mbuf  = (uint32_t*)d_ws;                                   // 128 KB
    float*    c_buf = (float*)((char*)d_ws + (128<<10));                 // 4 MB
    uint32_t* initT = (uint32_t*)((char*)d_ws + (128<<10) + (4<<20));    // 2 MB

    k_scanproj<<<CCH*NB_, 128, 0, stream>>>(U, lr, li, B, mult, Wx2y, bx2y, c_buf, Y);
    k_mid     <<<384, 64, 0, stream>>>(y0, lr, li, Wy2x, by2x, Wx2y, c_buf, initT, Mbuf);
    k_corr    <<<CCH*2, 256, 0, stream>>>((const _Float16*)Mbuf, initT, Y);
}

// Round 10
// 102.076 us; speedup vs baseline: 1.0593x; 1.0237x over previous
//
#include <hip/hip_runtime.h>
#include <math.h>

#define T_   2048
#define NB_  64
#define NU_  8
#define NY_  8
#define NH_  256
#define H2_  128
#define CCH  64      // number of chunks
#define LCH  32      // chunk length = T_/CCH

static const float PI_HALF = 1.5707963267948966f;

typedef _Float16 half8  __attribute__((ext_vector_type(8)));
typedef __fp16   fp16x2 __attribute__((ext_vector_type(2)));
typedef float    f32x4  __attribute__((ext_vector_type(4)));

// ws layout (bytes):
//   lamP  f32x4[128] (re,im,-im,re)      @ 0        2 KB
//   lamL  float2[128] (Lambda^L)         @ 2048     1 KB
//   Bs    f32[128][16] (B1s|B2s rows)    @ 4096     8 KB
//   Wm16  u32[8][128] pk(W[y][h],W[y][h+128]) @ 12288  4 KB
//   M     u32[256][128]                  @ 16384    128 KB
//   c_buf f32[k][b][pair][2]             @ 147456   4 MB
//   initT u32[k][b][128]                 @ 4341760  2 MB
#define OFF_LAMP  0
#define OFF_LAML  2048
#define OFF_BS    4096
#define OFF_WM16  12288
#define OFF_M     16384
#define OFF_CBUF  147456
#define OFF_INIT  4341760

// ---------------- kernel 0: coefficient precompute ----------------
__global__ __launch_bounds__(64) void k_pre(
    const float* __restrict__ lr, const float* __restrict__ li,
    const float* __restrict__ B, const float* __restrict__ mult,
    const float* __restrict__ Wx2y, char* __restrict__ ws)
{
    const int bi = blockIdx.x;
    const int j  = threadIdx.x;

    if (bi < 256) {
        // M[R=dlt*8+y][m]
        uint32_t* M32 = (uint32_t*)(ws + OFF_M);
        const int dlt = bi >> 3, y = bi & 7;
        const float e = (float)(dlt + 1);
        #pragma unroll
        for (int hh = 0; hh < 2; hh++) {
            const int h = j + hh*64;
            float r  = expf(-e * fabsf(lr[h]));
            float an = e * PI_HALF * li[h];
            float c = r * cosf(an), sn = r * sinf(an);
            float W1 = Wx2y[y*NH_ + h];
            float W2 = Wx2y[y*NH_ + h + H2_];
            float Mre = fmaf(W1, c,  W2 * sn);
            float Mim = fmaf(W2, c, -W1 * sn);
            union { fp16x2 h2; uint32_t u32; } pk;
            pk.h2 = __builtin_amdgcn_cvt_pkrtz(Mre, Mim);
            M32[bi*128 + hh*64 + j] = pk.u32;
        }
    } else if (bi == 256) {
        // lamP + lamL for pairs j, j+64
        float4* lamP = (float4*)(ws + OFF_LAMP);
        float2* lamL = (float2*)(ws + OFF_LAML);
        #pragma unroll
        for (int hh = 0; hh < 2; hh++) {
            const int h = j + hh*64;
            float a  = fabsf(lr[h]);
            float r  = expf(-a);
            float th = PI_HALF * li[h];
            float re = r * cosf(th), im = r * sinf(th);
            lamP[h] = make_float4(re, im, -im, re);
            float rL  = expf(-(float)LCH * a);
            float thL = (float)LCH * PI_HALF * li[h];
            lamL[h] = make_float2(rL * cosf(thL), rL * sinf(thL));
        }
    } else if (bi == 257) {
        // Bs[h][0..7] = B[h]*exp(mult[h]); Bs[h][8..15] = B[h+128]*exp(mult[h+128])
        float* Bs = (float*)(ws + OFF_BS);
        #pragma unroll
        for (int hh = 0; hh < 2; hh++) {
            const int h = j + hh*64;
            float s1 = expf(mult[h]), s2 = expf(mult[h+H2_]);
            #pragma unroll
            for (int i = 0; i < NU_; i++) {
                Bs[h*16 + i]     = B[h*NU_ + i]        * s1;
                Bs[h*16 + 8 + i] = B[(h+H2_)*NU_ + i]  * s2;
            }
        }
    } else {
        // Wm16[y][h] = pk(Wx2y[y][h], Wx2y[y][h+128])
        uint32_t* Wm = (uint32_t*)(ws + OFF_WM16);
        #pragma unroll
        for (int y = 0; y < NY_; y++) {
            #pragma unroll
            for (int hh = 0; hh < 2; hh++) {
                const int h = j + hh*64;
                union { fp16x2 h2; uint32_t u32; } pk;
                pk.h2 = __builtin_amdgcn_cvt_pkrtz(Wx2y[y*NH_ + h],
                                                   Wx2y[y*NH_ + h + H2_]);
                Wm[y*128 + h] = pk.u32;
            }
        }
    }
}

// ---------------- kernel 1: scan from zero + K-split MFMA projection ---------
// 128 threads = 2 waves. Thread tid owns pair h = tid (chans h, h+128).
__global__ __launch_bounds__(128) void k_scanproj(
    const float* __restrict__ U, const float* __restrict__ bx2y,
    const char* __restrict__ ws, float* __restrict__ c_buf,
    float* __restrict__ Y)
{
    const int k   = blockIdx.x >> 6;
    const int b   = blockIdx.x & 63;
    const int tid = threadIdx.x;
    const int h   = tid;
    const int w   = tid >> 6;
    const int l   = tid & 63;
    const int row = l & 15;
    const int kg  = (l >> 4) & 3;

    // packed coefficient loads (L2-hot, no transcendentals)
    const float4 lam = ((const float4*)(ws + OFF_LAMP))[h];   // re, im, -im, re
    float B1[NU_], B2[NU_];
    {
        const float4* bsp = (const float4*)(ws + OFF_BS) + h*4;
        float4 a0 = bsp[0], a1 = bsp[1], a2 = bsp[2], a3 = bsp[3];
        B1[0]=a0.x; B1[1]=a0.y; B1[2]=a0.z; B1[3]=a0.w;
        B1[4]=a1.x; B1[5]=a1.y; B1[6]=a1.z; B1[7]=a1.w;
        B2[0]=a2.x; B2[1]=a2.y; B2[2]=a2.z; B2[3]=a2.w;
        B2[4]=a3.x; B2[5]=a3.y; B2[6]=a3.z; B2[7]=a3.w;
    }
    half8 wf[4];
    {
        const uint32_t* Wm = (const uint32_t*)(ws + OFF_WM16);
        #pragma unroll
        for (int q2 = 0; q2 < 4; q2++) {
            const int q = 4*w + q2;
            union { uint4 u4; half8 h8; } fu;
            if (row < 8) fu.u4 = *(const uint4*)(Wm + row*128 + q*16 + kg*4);
            else         fu.u4 = make_uint4(0,0,0,0);
            wf[q2] = fu.h8;
        }
    }
    const float bias = bx2y[tid & 7];

    __shared__ float    uS[LCH*NU_];    // 1 KB
    __shared__ _Float16 xS[16*256];     // 8 KB
    __shared__ float    pS[4*132];
    uint32_t* xS32 = (uint32_t*)xS;

    if (tid < 64) {
        ((float4*)uS)[tid] =
            *(const float4*)(U + ((size_t)(k*LCH + (tid>>1))*NB_ + b)*NU_ + (tid&1)*4);
    }
    __syncthreads();

    float x1 = 0.f, x2 = 0.f;
    const int g = h >> 2;

    for (int s = 0; s < 2; s++) {
        #pragma unroll 4
        for (int t16 = 0; t16 < 16; t16++) {
            const int t = s*16 + t16;
            float4 u0 = ((const float4*)uS)[2*t+0];
            float4 u1 = ((const float4*)uS)[2*t+1];
            float u[NU_] = {u0.x,u0.y,u0.z,u0.w,u1.x,u1.y,u1.z,u1.w};
            float bu1=0.f, bu2=0.f;
            #pragma unroll
            for (int i = 0; i < NU_; i++) {
                bu1 = fmaf(u[i], B1[i], bu1);
                bu2 = fmaf(u[i], B2[i], bu2);
            }
            float n1 = fmaf(lam.x, x1, fmaf(lam.z, x2, bu1));
            float n2 = fmaf(lam.y, x1, fmaf(lam.w, x2, bu2));
            x1 = n1; x2 = n2;

            union { fp16x2 h2; uint32_t u32; } pk;
            pk.h2 = __builtin_amdgcn_cvt_pkrtz(x1, x2);
            xS32[t16*128 + ((g ^ t16) & 31)*4 + (h & 3)] = pk.u32;
        }
        __syncthreads();

        f32x4 acc = {0.f,0.f,0.f,0.f};
        #pragma unroll
        for (int q2 = 0; q2 < 4; q2++) {
            const int q = 4*w + q2;
            const int p = ((q << 2) + kg) ^ row;
            const half8* ap = (const half8*)(xS + (row << 8) + (p << 3));
            acc = __builtin_amdgcn_mfma_f32_16x16x32_f16(*ap, wf[q2], acc, 0, 0, 0);
        }
        #pragma unroll
        for (int r = 0; r < 4; r++) pS[r*132 + w*64 + l] = acc[r];
        __syncthreads();

        {
            const int t  = tid >> 3, y = tid & 7;
            const int ls = ((t >> 2) << 4) + y;
            const int rg = t & 3;
            float sum = pS[rg*132 + ls] + pS[rg*132 + 64 + ls];
            Y[((size_t)(k*LCH + s*16 + t)*NB_ + b)*NY_ + y] = sum + bias;
        }
    }

    *(float2*)(c_buf + (size_t)(k*NB_ + b)*(H2_*2) + 2*h) = make_float2(x1, x2);
}

// ---------------- kernel 2: chunk prefix -> f16 transposed inits --------------
__global__ __launch_bounds__(64) void k_prefix(
    const float* __restrict__ y0, const float* __restrict__ Wy2x,
    const float* __restrict__ by2x, const char* __restrict__ ws,
    const float* __restrict__ c_buf, uint32_t* __restrict__ initT)
{
    const int g = blockIdx.x*64 + threadIdx.x;
    const int b = g >> 7;
    const int h = g & 127;

    float x1 = by2x[h], x2 = by2x[h+H2_];
    #pragma unroll
    for (int y = 0; y < NY_; y++) {
        float yy = y0[b*NY_ + y];
        x1 = fmaf(yy, Wy2x[h*NY_ + y],        x1);
        x2 = fmaf(yy, Wy2x[(h+H2_)*NY_ + y],  x2);
    }

    const float2 lL = ((const float2*)(ws + OFF_LAML))[h];
    const float reL = lL.x, imL = lL.y;

    #pragma unroll 8
    for (int k = 0; k < CCH; k++) {
        float2 c = *(const float2*)(c_buf + (size_t)k*16384 + b*256 + 2*h);
        union { fp16x2 hh; uint32_t u32; } pk;
        pk.hh = __builtin_amdgcn_cvt_pkrtz(x1, x2);
        initT[(size_t)k*8192 + b*128 + h] = pk.u32;
        float n1 = fmaf(reL, x1, fmaf(-imL, x2, c.x));
        float n2 = fmaf(imL, x1, fmaf( reL, x2, c.y));
        x1 = n1; x2 = n2;
    }
}

// ---------------- kernel 3: correction GEMM, Y += M @ init_k -----------------
// 512 blocks = (k, b-half, R-tile-group); 256 threads = 4 waves, 1 R-tile/wave.
// bS staging: 256 threads x 16 dwords = full 32 rows x 128 dwords.
__global__ __launch_bounds__(256) void k_corr(
    const _Float16* __restrict__ M, const uint32_t* __restrict__ initT,
    float* __restrict__ Y)
{
    const int bi   = blockIdx.x;
    const int k    = bi >> 3;
    const int half = (bi >> 2) & 1;
    const int rtg  = bi & 3;
    const int tid  = threadIdx.x;
    const int w    = tid >> 6, l = tid & 63;
    const int lane16 = l & 15, kg = l >> 4;

    __shared__ _Float16 bS[32*264];
    {
        uint32_t* bS32 = (uint32_t*)bS;
        const int r = tid >> 3, seg = tid & 7;
        const uint32_t* src = initT + (size_t)k*8192 + (half*32 + r)*128 + seg*16;
        uint32_t* dst = bS32 + r*132 + seg*16;
        ((uint4*)dst)[0] = ((const uint4*)src)[0];
        ((uint4*)dst)[1] = ((const uint4*)src)[1];
        ((uint4*)dst)[2] = ((const uint4*)src)[2];
        ((uint4*)dst)[3] = ((const uint4*)src)[3];
    }
    __syncthreads();

    const int R0 = rtg*64 + w*16;
    half8 af[8];
    #pragma unroll
    for (int q = 0; q < 8; q++)
        af[q] = *(const half8*)(M + (size_t)(R0 + lane16)*256 + q*32 + kg*8);

    f32x4 acc0 = {0.f,0.f,0.f,0.f}, acc1 = {0.f,0.f,0.f,0.f};
    #pragma unroll
    for (int q = 0; q < 8; q++) {
        const half8* b0 = (const half8*)(bS + ( 0 + lane16)*264 + q*32 + kg*8);
        const half8* b1 = (const half8*)(bS + (16 + lane16)*264 + q*32 + kg*8);
        acc0 = __builtin_amdgcn_mfma_f32_16x16x32_f16(af[q], *b0, acc0, 0, 0, 0);
        acc1 = __builtin_amdgcn_mfma_f32_16x16x32_f16(af[q], *b1, acc1, 0, 0, 0);
    }

    const int t  = k*LCH + (R0 >> 3) + (kg >> 1);
    const int y0 = (kg & 1) * 4;
    float4* yp0 = (float4*)(Y + ((size_t)t*NB_ + half*32 +  0 + lane16)*NY_ + y0);
    float4* yp1 = (float4*)(Y + ((size_t)t*NB_ + half*32 + 16 + lane16)*NY_ + y0);
    float4 o0 = *yp0, o1 = *yp1;
    o0.x += acc0[0]; o0.y += acc0[1]; o0.z += acc0[2]; o0.w += acc0[3];
    o1.x += acc1[0]; o1.y += acc1[1]; o1.z += acc1[2]; o1.w += acc1[3];
    *yp0 = o0; *yp1 = o1;
}

extern "C" void kernel_launch(void* const* d_in, const int* in_sizes, int n_in,
                              void* d_out, int out_size, void* d_ws, size_t ws_size,
                              hipStream_t stream) {
    const float* y0   = (const float*)d_in[0];
    const float* U    = (const float*)d_in[1];
    const float* lr   = (const float*)d_in[2];
    const float* li   = (const float*)d_in[3];
    const float* B    = (const float*)d_in[4];
    const float* mult = (const float*)d_in[5];
    const float* Wy2x = (const float*)d_in[6];
    const float* by2x = (const float*)d_in[7];
    const float* Wx2y = (const float*)d_in[8];
    const float* bx2y = (const float*)d_in[9];
    float* Y = (float*)d_out;

    char*     ws    = (char*)d_ws;
    float*    c_buf = (float*)(ws + OFF_CBUF);
    uint32_t* initT = (uint32_t*)(ws + OFF_INIT);
    const _Float16* Mf = (const _Float16*)(ws + OFF_M);

    k_pre     <<<259, 64, 0, stream>>>(lr, li, B, mult, Wx2y, ws);
    k_scanproj<<<CCH*NB_, 128, 0, stream>>>(U, bx2y, ws, c_buf, Y);
    k_prefix  <<<(NB_*H2_)/64, 64, 0, stream>>>(y0, Wy2x, by2x, ws, c_buf, initT);
    k_corr    <<<CCH*8, 256, 0, stream>>>(Mf, initT, Y);
}